// Round 5
// baseline (499.613 us; speedup 1.0000x reference)
//
#include <hip/hip_runtime.h>

// ChaosModulator v4b: chunk-parallel recurrence + LDS-transposed I/O,
// non-temporal u stores, 32KB LDS for 4-5 blocks/CU.
// (v4 with the nontemporal-store compile fix: cast float4* to a native
// clang ext_vector pointer -- HIP_vector_type is rejected by the builtin.)
//
//   sigma = 3.5*z*(1-z) + 0.5*x_t
//   z'    = 0.5*z + 0.5*sigmoid(2*sigma)   (clip is a no-op)
//   u_t   = 0.5*x_t + z' - 0.5
//
// v3 post-mortem: WRITE_SIZE was 1.98x ideal -- u write-allocates and
// stream-evicts through L2/L3 (also evicting the L3-resident x). u is
// write-once/never-read: store it non-temporally. Occupancy was 20%
// (64KB LDS, 2 blocks/CU) with BW efficiency 67%; halving the stage to
// 16 t-steps gives 32KB LDS -> 4-5 blocks/CU of independent barrier
// groups.
//
// Geometry: block = 256 thr = 16 seqs x 16 chunks (CHUNK=256 t-steps).
// Stage = 16 t-steps = 4 float4/piece; 16 stages; 16KB staged per stage.
// LDS layout slot(p,q) = q*256 + p:
//   - compute phase reads q*256+tid  -> wave-contiguous 1KB (b128 floor)
//   - stage/store phase (16 pieces x 64B per inst) hits all banks evenly
// Global I/O: per instruction 16 pieces x 64B contiguous = full lines.
// Warmup (64-step contraction burn-in, |dz'/dz| ~ 0.25..0.75 on the
// realized orbit) replays the neighbor piece's stage 12..15 windows from
// LDS in two rounds; state error after 64 steps < 1e-6 << tolerance.

#define SEQ_T   4096
#define CHUNK   256
#define NSTAGE  16          // stages per chunk, 16 t-steps each
#define WF4     4           // float4s per stage window
#define SEQ_PB  16          // sequences per block
#define NPIECE  256         // pieces (=threads) per block

typedef float fx4 __attribute__((ext_vector_type(4)));

__device__ __forceinline__ void chaos_step(float& z, float xs, float& us) {
    const float CA = -10.098865286222744f;  // 3.5 * (-2*log2(e))
    const float CB = -1.4426950408889634f;  // 0.5 * (-2*log2(e))
    float p  = CB * xs;                         // off-chain
    float hz = 0.5f * z;                        // parallel path
    float zz = __builtin_fmaf(-z, z, z);        // z - z^2     (chain)
    float s  = __builtin_fmaf(CA, zz, p);       // -2*log2e*sigma
    float e  = exp2f(s);                        // v_exp_f32
    float r  = __builtin_amdgcn_rcpf(e + 1.0f); // sigmoid(2*sigma)
    z = __builtin_fmaf(0.5f, r, hz);            // z' = 0.5z + 0.5*sig
    us = __builtin_fmaf(0.5f, xs, z - 0.5f);    // u  (off-chain)
}

__global__ __launch_bounds__(256, 4)
void ChaosModulator_28922309771717_kernel(const float* __restrict__ x,
                                          const float* __restrict__ z0,
                                          float* __restrict__ u) {
    __shared__ float4 lds[2][NPIECE * WF4];     // 2 x 16 KiB

    const int tid  = threadIdx.x;
    const int lane = tid & 63;
    const int wid  = tid >> 6;
    const int q4   = lane & 3;      // float4 index within a piece's window
    const int pr   = lane >> 2;     // piece-row within group of 16 (0..15)

    const size_t blk_elem = (size_t)blockIdx.x * SEQ_PB * SEQ_T;
    const float4* __restrict__ xb = (const float4*)(x + blk_elem);
    fx4*          __restrict__ ub = (fx4*)(u + blk_elem);

    // Staging geometry: instruction j handles piece p_j = wid*64 + j*16 + pr,
    // float4 q4 of its stage window. 4 lanes -> 64B contiguous per piece,
    // 16 pieces per instruction.
    int o4[WF4];   // global float4 index at stage 0
    int sl[WF4];   // LDS slot
#pragma unroll
    for (int j = 0; j < WF4; ++j) {
        int p = wid * 64 + j * 16 + pr;
        o4[j] = (p >> 4) * (SEQ_T / 4) + (p & 15) * (CHUNK / 4) + q4;
        sl[j] = q4 * NPIECE + p;
    }

    float4 g[WF4];

    // ---- warmup round A: stage-12 window -> lds[0], stage-13 -> lds[1]
#pragma unroll
    for (int j = 0; j < WF4; ++j) g[j] = xb[o4[j] + 12 * WF4];
#pragma unroll
    for (int j = 0; j < WF4; ++j) lds[0][sl[j]] = g[j];
#pragma unroll
    for (int j = 0; j < WF4; ++j) g[j] = xb[o4[j] + 13 * WF4];
#pragma unroll
    for (int j = 0; j < WF4; ++j) lds[1][sl[j]] = g[j];
    __syncthreads();

    // ---- warmup: replay the 64 x-values preceding this chunk (= neighbor
    // piece's stages 12..15). chunk-0 threads compute garbage and reload z0.
    float z = 0.5f;
    const int pn = (tid == 0) ? 0 : tid - 1;
    float du;
#pragma unroll
    for (int b = 0; b < 2; ++b) {
#pragma unroll
        for (int q = 0; q < WF4; ++q) {
            float4 w = lds[b][q * NPIECE + pn];
            chaos_step(z, w.x, du); chaos_step(z, w.y, du);
            chaos_step(z, w.z, du); chaos_step(z, w.w, du);
        }
    }
    __syncthreads();    // round-A reads done before round-B staging

    // ---- warmup round B: stage-14 -> lds[0], stage-15 -> lds[1]
#pragma unroll
    for (int j = 0; j < WF4; ++j) g[j] = xb[o4[j] + 14 * WF4];
#pragma unroll
    for (int j = 0; j < WF4; ++j) lds[0][sl[j]] = g[j];
#pragma unroll
    for (int j = 0; j < WF4; ++j) g[j] = xb[o4[j] + 15 * WF4];
#pragma unroll
    for (int j = 0; j < WF4; ++j) lds[1][sl[j]] = g[j];
    __syncthreads();

#pragma unroll
    for (int b = 0; b < 2; ++b) {
#pragma unroll
        for (int q = 0; q < WF4; ++q) {
            float4 w = lds[b][q * NPIECE + pn];
            chaos_step(z, w.x, du); chaos_step(z, w.y, du);
            chaos_step(z, w.z, du); chaos_step(z, w.w, du);
        }
    }
    if ((tid & 15) == 0) z = z0[blockIdx.x * SEQ_PB + (tid >> 4)];
    __syncthreads();    // warmup reads done; buffers reusable

    // ---- prologue: stage 0 -> lds[0]
#pragma unroll
    for (int j = 0; j < WF4; ++j) g[j] = xb[o4[j]];
#pragma unroll
    for (int j = 0; j < WF4; ++j) lds[0][sl[j]] = g[j];
    __syncthreads();

    // ---- main pipeline: prefetch s+1 during compute of s
    for (int s = 0; s < NSTAGE; ++s) {
        float4* cur = lds[s & 1];
        float4* nxt = lds[(s + 1) & 1];

        if (s + 1 < NSTAGE) {
#pragma unroll
            for (int j = 0; j < WF4; ++j) g[j] = xb[o4[j] + (s + 1) * WF4];
        }

        // 16 recurrence steps, in place (x slot -> u slot), own piece only.
        // Reads are wave-contiguous: slot q*256+tid -> lane*16B.
#pragma unroll
        for (int q = 0; q < WF4; ++q) {
            const int slot = q * NPIECE + tid;
            float4 xv = cur[slot];
            float4 uq;
            chaos_step(z, xv.x, uq.x); chaos_step(z, xv.y, uq.y);
            chaos_step(z, xv.z, uq.z); chaos_step(z, xv.w, uq.w);
            cur[slot] = uq;
        }
        __syncthreads();

        // ds_write of prefetched x first, then the full-line coalesced
        // non-temporal u store (u is write-once: don't allocate in L2/L3,
        // don't evict the L3-resident x).
        if (s + 1 < NSTAGE) {
#pragma unroll
            for (int j = 0; j < WF4; ++j) nxt[sl[j]] = g[j];
        }
#pragma unroll
        for (int j = 0; j < WF4; ++j) {
            float4 uq = cur[sl[j]];
            fx4 uv = { uq.x, uq.y, uq.z, uq.w };
            __builtin_nontemporal_store(uv, &ub[o4[j] + s * WF4]);
        }

        __syncthreads();
    }
}

extern "C" void kernel_launch(void* const* d_in, const int* in_sizes, int n_in,
                              void* d_out, int out_size, void* d_ws, size_t ws_size,
                              hipStream_t stream) {
    const float* x  = (const float*)d_in[0];   // (32, 512, 4096)
    const float* z0 = (const float*)d_in[1];   // (32, 512)
    float* u = (float*)d_out;                  // (32, 512, 4096)

    const int n_seq = in_sizes[1];             // 16384
    dim3 grid(n_seq / SEQ_PB), block(NPIECE);  // 1024 blocks x 256 thr
    ChaosModulator_28922309771717_kernel<<<grid, block, 0, stream>>>(x, z0, u);
}